// Round 2
// 317.055 us; speedup vs baseline: 1.0436x; 1.0436x over previous
//
#include <hip/hip_runtime.h>
#include <math.h>

#define NCH 4096          // channel count (images)
#define IMG 64            // image side
#define HW  (IMG * IMG)   // 4096 pixels per image
#define NM  4             // number of multiplier kernels

// Native 4-float vector for __builtin_nontemporal_store (HIP's float4 class
// type is rejected by the builtin; this alias is layout-identical).
typedef float nfloat4 __attribute__((ext_vector_type(4)));

// Halo-padded LDS tile: rows 0..65 (64 interior + zero border), stride 69.
// 69 is odd -> row-group bank offsets (h+1)*69 mod 32 = 5*(h+1) land in all 4
// residue classes mod 4, so a wave's 4 row-groups hit disjoint bank sets:
// 64 lanes / 32 banks = free 2-way aliasing on both ds_write (stage) and
// ds_read (taps). Border cells are zeroed once per block -> tap loads need
// NO bounds checks (was 72 cmp + 72 cndmask per thread).
#define TP    69
#define TROWS 66
#define TILE_FLOATS (TROWS * TP)

#define GRID1 1024              // pass-1 blocks
#define CPB1  (NCH / GRID1)     // 4 channels per pass-1 block

// ws layout (floats): [0 .. GRID1*NM) per-block partial maxima (float4 each)

__device__ __forceinline__ void load_weights(const float* __restrict__ wgt,
                                             const float* __restrict__ wf,
                                             float k[NM][9]) {
#pragma unroll
    for (int n = 0; n < NM; ++n) {
        float f = fminf(fmaxf(wf[n], 1.0f), 255.0f);             // clip(weight_factor, 1, 255)
#pragma unroll
        for (int j = 0; j < 9; ++j) {
            float w = fminf(fmaxf(wgt[n * 9 + j], -1.0f), 1.0f); // clip(weight, -1, 1)
            k[n][j] = w * f;
        }
    }
}

// Zero the 260 border cells of the padded tile (rows 0,65; cols 0,65).
__device__ __forceinline__ void zero_border(float* tile, int t) {
#pragma unroll
    for (int b = t; b < 260; b += 256) {
        int r, cidx;
        if (b < 66)       { r = 0;            cidx = b; }
        else if (b < 132) { r = 65;           cidx = b - 66; }
        else if (b < 196) { r = b - 132 + 1;  cidx = 0; }
        else              { r = b - 196 + 1;  cidx = 65; }
        tile[r * TP + cidx] = 0.0f;
    }
}

// Stage one 64x64 image into the interior of the padded tile.
__device__ __forceinline__ void stage_tile(const float* __restrict__ img,
                                           float* tile, int t) {
    const float4* img4 = (const float4*)img;
#pragma unroll
    for (int i = 0; i < 4; ++i) {
        int idx = t + i * 256;       // float4 index 0..1023
        float4 v = img4[idx];
        int p = idx * 4;
        int h = p >> 6;
        int w = p & 63;
        float* dst = &tile[(h + 1) * TP + (w + 1)];
        dst[0] = v.x; dst[1] = v.y; dst[2] = v.z; dst[3] = v.w;
    }
}

// Load the 3x6 tap window for pixels (h, w0..w0+3) from the padded tile.
// Padded coords: pixel (h,w) lives at tile[(h+1)*TP + (w+1)]; window rows
// h-1..h+1 -> padded h..h+2, cols w0-1..w0+4 -> padded w0..w0+5. Unconditional.
__device__ __forceinline__ void load_taps(const float* tile, int h, int w0,
                                          float tap[3][6]) {
#pragma unroll
    for (int r = 0; r < 3; ++r) {
        const float* row = &tile[(h + r) * TP + w0];
#pragma unroll
        for (int cdx = 0; cdx < 6; ++cdx)
            tap[r][cdx] = row[cdx];
    }
}

__global__ __launch_bounds__(256) void conv_max_kernel(
        const float* __restrict__ in, const float* __restrict__ wgt,
        const float* __restrict__ wf, float* __restrict__ ws) {
    __shared__ float tile[TILE_FLOATS];
    __shared__ float red[4][NM];
    const int t = threadIdx.x;

    float k[NM][9];
    load_weights(wgt, wf, k);
    zero_border(tile, t);

    float m[NM] = {-INFINITY, -INFINITY, -INFINITY, -INFINITY};

#pragma unroll
    for (int cc = 0; cc < CPB1; ++cc) {
        const int c = blockIdx.x * CPB1 + cc;
        const float* img = in + (size_t)c * HW;
        __syncthreads();                 // border done (cc=0) / prev compute done
        stage_tile(img, tile, t);
        __syncthreads();

#pragma unroll
        for (int g = 0; g < 4; ++g) {
            int pix = (t + g * 256) * 4;   // 4 consecutive pixels in one row
            int h = pix >> 6;
            int w0 = pix & 63;
            float tap[3][6];
            load_taps(tile, h, w0, tap);
#pragma unroll
            for (int i = 0; i < 4; ++i) {
#pragma unroll
                for (int n = 0; n < NM; ++n) {
                    float acc = 0.0f;
#pragma unroll
                    for (int dy = 0; dy < 3; ++dy)
#pragma unroll
                        for (int dx = 0; dx < 3; ++dx)
                            acc = fmaf(k[n][dy * 3 + dx], tap[dy][dx + i], acc);
                    m[n] = fmaxf(m[n], acc);
                }
            }
        }
    }

    // wave (64-lane) shuffle max reduce
#pragma unroll
    for (int off = 32; off >= 1; off >>= 1)
#pragma unroll
        for (int n = 0; n < NM; ++n)
            m[n] = fmaxf(m[n], __shfl_down(m[n], off, 64));

    const int wave = t >> 6, lane = t & 63;
    if (lane == 0)
#pragma unroll
        for (int n = 0; n < NM; ++n) red[wave][n] = m[n];
    __syncthreads();
    if (t == 0) {
        float4 v;
        v.x = fmaxf(fmaxf(red[0][0], red[1][0]), fmaxf(red[2][0], red[3][0]));
        v.y = fmaxf(fmaxf(red[0][1], red[1][1]), fmaxf(red[2][1], red[3][1]));
        v.z = fmaxf(fmaxf(red[0][2], red[1][2]), fmaxf(red[2][2], red[3][2]));
        v.w = fmaxf(fmaxf(red[0][3], red[1][3]), fmaxf(red[2][3], red[3][3]));
        *(float4*)(ws + (size_t)blockIdx.x * NM) = v;
    }
}

__global__ __launch_bounds__(256) void conv_out_kernel(
        const float* __restrict__ in, const float* __restrict__ wgt,
        const float* __restrict__ wf, const float* __restrict__ ws,
        float* __restrict__ out) {
    __shared__ float tile[TILE_FLOATS];
    __shared__ float red[4][NM];
    const int c = blockIdx.x;
    const int t = threadIdx.x;
    const float* img = in + (size_t)c * HW;

    // Redundant per-block reduce of the 1024 float4 partials (16 KB, L2/L3
    // resident). Replaces the single-block reduce kernel that idled the whole
    // GPU between the two big dispatches. Kernel-boundary release/acquire
    // makes pass-1 partials coherent here without atomics.
    const float4* p4 = (const float4*)ws;
    float4 mm = {-INFINITY, -INFINITY, -INFINITY, -INFINITY};
#pragma unroll
    for (int i = 0; i < GRID1 / 256; ++i) {
        float4 v = p4[t + i * 256];
        mm.x = fmaxf(mm.x, v.x); mm.y = fmaxf(mm.y, v.y);
        mm.z = fmaxf(mm.z, v.z); mm.w = fmaxf(mm.w, v.w);
    }
#pragma unroll
    for (int off = 32; off >= 1; off >>= 1) {
        mm.x = fmaxf(mm.x, __shfl_down(mm.x, off, 64));
        mm.y = fmaxf(mm.y, __shfl_down(mm.y, off, 64));
        mm.z = fmaxf(mm.z, __shfl_down(mm.z, off, 64));
        mm.w = fmaxf(mm.w, __shfl_down(mm.w, off, 64));
    }
    const int wave = t >> 6, lane = t & 63;
    if (lane == 0) {
        red[wave][0] = mm.x; red[wave][1] = mm.y;
        red[wave][2] = mm.z; red[wave][3] = mm.w;
    }
    __syncthreads();
    float fin[NM];
#pragma unroll
    for (int n = 0; n < NM; ++n)
        fin[n] = fmaxf(fmaxf(red[0][n], red[1][n]), fmaxf(red[2][n], red[3][n]));

    float inv[NM];
#pragma unroll
    for (int n = 0; n < NM; ++n) {
        float div = fin[n] * (1.0f / 128.0f);
        if (div > 0.0f) {
            float shift = rintf(log2f(div));   // round-half-even == jnp.round
            inv[n] = exp2f(-shift);            // exact power of 2
        } else {
            inv[n] = 1.0f;                     // where(div>0, shifted, result)
        }
    }

    float k[NM][9];
    load_weights(wgt, wf, k);

    __syncthreads();            // red[] reads done before tile phase reuses LDS
    zero_border(tile, t);
    stage_tile(img, tile, t);
    __syncthreads();

#pragma unroll
    for (int g = 0; g < 4; ++g) {
        int pix = (t + g * 256) * 4;
        int h = pix >> 6;
        int w0 = pix & 63;
        float tap[3][6];
        load_taps(tile, h, w0, tap);
#pragma unroll
        for (int n = 0; n < NM; ++n) {
            nfloat4 o;
#pragma unroll
            for (int i = 0; i < 4; ++i) {
                float acc = 0.0f;
#pragma unroll
                for (int dy = 0; dy < 3; ++dy)
#pragma unroll
                    for (int dx = 0; dx < 3; ++dx)
                        acc = fmaf(k[n][dy * 3 + dx], tap[dy][dx + i], acc);
                o[i] = tap[1][i + 1] + acc * inv[n];   // input + shifted conv
            }
            size_t off = ((size_t)n * NCH + c) * HW + pix;
            // Non-temporal: 268 MB output stream must not evict the 64 MiB
            // input from L2/L3 (pass-2 input reads are L3 hits).
            __builtin_nontemporal_store(o, (nfloat4*)(out + off));
        }
    }
}

extern "C" void kernel_launch(void* const* d_in, const int* in_sizes, int n_in,
                              void* d_out, int out_size, void* d_ws, size_t ws_size,
                              hipStream_t stream) {
    const float* in  = (const float*)d_in[0];   // [1,4096,64,64]
    const float* wgt = (const float*)d_in[1];   // [4,9]
    const float* wf  = (const float*)d_in[2];   // [4,1]
    float* out = (float*)d_out;                 // [4,1,4096,64,64]
    float* ws  = (float*)d_ws;                  // 1024 partial float4 maxima

    conv_max_kernel<<<dim3(GRID1), dim3(256), 0, stream>>>(in, wgt, wf, ws);
    conv_out_kernel<<<dim3(NCH), dim3(256), 0, stream>>>(in, wgt, wf, ws, out);
}